// Round 7
// baseline (144.048 us; speedup 1.0000x reference)
//
#include <hip/hip_runtime.h>
#include <hip/hip_bf16.h>
#include <cstdint>
#include <cstddef>

#define B_ROWS 4096
#define D_DIM  256
#define TWOB   8192
static constexpr float kScale = 2.8853900817779268f; // log2(e)/TEMPERATURE, T=0.5

typedef __bf16 bf16_t;
typedef __bf16 bf16x4 __attribute__((ext_vector_type(4)));
typedef __bf16 bf16x8 __attribute__((ext_vector_type(8)));
typedef float  f32x4  __attribute__((ext_vector_type(4)));

// ---- workspace layout ----
#define WS_Z    0ull                                  // bf16 [8192][256], group-swizzled per row
#define WS_KEYS ((size_t)TWOB * D_DIM * 2)            // i32 [8192]
#define WS_DEN  (WS_KEYS + (size_t)TWOB * 4)          // f32 [8192]
#define WS_PAIR (WS_DEN + (size_t)TWOB * 4)           // f32 [4096]
#define WS_CNT  (WS_PAIR + (size_t)B_ROWS * 4)        // i32 [1] completion counter

// Swizzle: within each 64-elem K-chunk (128 B), the 8 16B-groups are permuted
// by XOR with (row&7), baked into the GLOBAL layout so linear global_load_lds
// staging lands pre-swizzled in LDS (m173) and ds_read_b128 fragment reads are
// bank-conflict-free (verified: SQ_LDS_BANK_CONFLICT == 0 in R3/R5).

// ---------------- kernel 1: normalize + bf16 swizzled store + keys + zeroing + pair dots ----------------
__global__ __launch_bounds__(256) void prep_kernel(
    const float* __restrict__ emb_i, const float* __restrict__ emb_j,
    const int* __restrict__ tags, const int* __restrict__ docs,
    bf16_t* __restrict__ Z, int* __restrict__ keys,
    float* __restrict__ denom, float* __restrict__ pair, int* __restrict__ cnt)
{
  __shared__ float4 zbuf[4][64];
  const int t = threadIdx.x;
  const int lane = t & 63, w = t >> 6;
  const int b = blockIdx.x;                     // 2048 blocks
  const int rlocal = 2 * b + (w & 1);
  const int row = rlocal + (w >> 1) * B_ROWS;
  const float* src = (w >> 1) ? (emb_j + (size_t)rlocal * D_DIM)
                              : (emb_i + (size_t)rlocal * D_DIM);
  float4 v = *(const float4*)(src + lane * 4);
  float ss = v.x * v.x + v.y * v.y + v.z * v.z + v.w * v.w;
  #pragma unroll
  for (int m = 32; m; m >>= 1) ss += __shfl_xor(ss, m, 64);
  float inv = 1.0f / sqrtf(ss);
  float4 z = {v.x * inv, v.y * inv, v.z * inv, v.w * inv};
  zbuf[w][lane] = z;

  bf16x4 q;
  q[0] = (bf16_t)z.x; q[1] = (bf16_t)z.y; q[2] = (bf16_t)z.z; q[3] = (bf16_t)z.w;
  int chunk = lane >> 4;
  int g     = (lane >> 1) & 7;
  int gs    = g ^ (row & 7);
  int half  = lane & 1;
  *(bf16x4*)(Z + (size_t)row * D_DIM + chunk * 64 + gs * 8 + half * 4) = q;

  if (lane == 0) {
    keys[row] = (tags[rlocal] << 16) | docs[rlocal];  // tag<100 (7b) | doc<512 (9b)
    denom[row] = 0.f;
  }
  if (b == 0 && t == 0) cnt[0] = 0;
  __syncthreads();
  if (w < 2) {  // pair dot from fp32 z (pre-rounding)
    float4 a = zbuf[w][lane], c = zbuf[w + 2][lane];
    float d = a.x * c.x + a.y * c.y + a.z * c.z + a.w * c.w;
    #pragma unroll
    for (int m = 32; m; m >>= 1) d += __shfl_xor(d, m, 64);
    if (lane == 0) pair[2 * b + w] = d;
  }
}

// ---------------- kernel 2: triangular fused sim-GEMM + exp + mask + sums + final reduction ----------------
#define BM 128
#define BK 64
#define NKT (D_DIM / BK)   // 4 K-steps per tile
#define STRIP 4            // tiles per block; 2080/4 = 520 blocks (= 65 per XCD)
#define TOT (STRIP * NKT)  // 16 seamless double-buffered K-steps
#define NBLK 520

__global__ __launch_bounds__(256, 2) void fused_kernel(
    const bf16_t* __restrict__ Z, const int* __restrict__ keys,
    float* __restrict__ denom, const float* __restrict__ pair,
    int* __restrict__ cnt, float* __restrict__ out)
{
  __shared__ bf16_t sA[2][BM * BK];   // 2 x 16 KB
  __shared__ bf16_t sB[2][BM * BK];   // 2 x 16 KB
  __shared__ int s_last;
  __shared__ float s_red[4];
  const int tid  = threadIdx.x;
  const int lane = tid & 63;
  const int w    = tid >> 6;
  const int wr = w >> 1, wc = w & 1;           // 2x2 waves, each 64x64 output
  const int l15 = lane & 15, l4 = lane >> 4;

  // XCD-aware bijective swizzle (520 = 8 * 65)
  const int bid = (blockIdx.x % 8) * (NBLK / 8) + blockIdx.x / 8;

  // decode tile t0 = 4*bid, then the next 3 in triangle order
  int t0 = 4 * bid;
  int rt = (int)((sqrtf(8.0f * (float)t0 + 1.0f) - 1.0f) * 0.5f);
  while ((rt + 1) * (rt + 2) / 2 <= t0) ++rt;
  while (rt * (rt + 1) / 2 > t0) --rt;
  int ct = t0 - rt * (rt + 1) / 2;
  int r0s[STRIP], c0s[STRIP];
  bool od[STRIP];
  #pragma unroll
  for (int i = 0; i < STRIP; ++i) {
    r0s[i] = rt * BM; c0s[i] = ct * BM; od[i] = (rt != ct);
    if (++ct > rt) { ++rt; ct = 0; }
  }

  f32x4 acc[4][4];
  const f32x4 vzero = {0.f, 0.f, 0.f, 0.f};
  #pragma unroll
  for (int mi = 0; mi < 4; ++mi)
    #pragma unroll
    for (int ni = 0; ni < 4; ++ni) acc[mi][ni] = vzero;

  // stage both 128x64 tiles of (tile ti, K-step kt) into buf: 8 loads/thread
  auto STAGE = [&](int buf, int ti, int kt) {
    #pragma unroll
    for (int i = 0; i < 4; ++i) {
      int o  = i * 4096 + tid * 16;            // byte offset within 16KB tile
      int rl = o >> 7, ob = o & 127;
      const bf16_t* ga = Z + (size_t)(r0s[ti] + rl) * D_DIM + kt * 64 + (ob >> 1);
      __builtin_amdgcn_global_load_lds(
          (const __attribute__((address_space(1))) void*)ga,
          (__attribute__((address_space(3))) void*)((char*)&sA[buf][0] + o), 16, 0, 0);
      const bf16_t* gb = Z + (size_t)(c0s[ti] + rl) * D_DIM + kt * 64 + (ob >> 1);
      __builtin_amdgcn_global_load_lds(
          (const __attribute__((address_space(1))) void*)gb,
          (__attribute__((address_space(3))) void*)((char*)&sB[buf][0] + o), 16, 0, 0);
    }
  };

  auto EPI = [&](int ti) {
    const int row0 = r0s[ti], col0 = c0s[ti];
    int keyr[4][4];
    #pragma unroll
    for (int mi = 0; mi < 4; ++mi)
      #pragma unroll
      for (int j = 0; j < 4; ++j)
        keyr[mi][j] = keys[row0 + wr * 64 + mi * 16 + l4 * 4 + j];
    int keyc[4];
    #pragma unroll
    for (int ni = 0; ni < 4; ++ni)
      keyc[ni] = keys[col0 + wc * 64 + ni * 16 + l15];

    float rowsum[4][4];
    #pragma unroll
    for (int mi = 0; mi < 4; ++mi)
      #pragma unroll
      for (int j = 0; j < 4; ++j) rowsum[mi][j] = 0.f;
    float colsum[4] = {0.f, 0.f, 0.f, 0.f};

    #pragma unroll
    for (int ni = 0; ni < 4; ++ni) {
      #pragma unroll
      for (int mi = 0; mi < 4; ++mi) {
        #pragma unroll
        for (int j = 0; j < 4; ++j) {
          int x = keyr[mi][j] ^ keyc[ni];
          bool m = ((x >> 16) != 0) & ((x & 0xFFFF) != 0);
          float e = m ? __builtin_amdgcn_exp2f(acc[mi][ni][j] * kScale) : 0.f;
          rowsum[mi][j] += e;
          colsum[ni] += e;
        }
      }
    }
    #pragma unroll
    for (int mi = 0; mi < 4; ++mi)
      #pragma unroll
      for (int j = 0; j < 4; ++j) {
        float v = rowsum[mi][j];
        v += __shfl_xor(v, 1, 64);
        v += __shfl_xor(v, 2, 64);
        v += __shfl_xor(v, 4, 64);
        v += __shfl_xor(v, 8, 64);
        if (l15 == 0)
          atomicAdd(&denom[row0 + wr * 64 + mi * 16 + l4 * 4 + j], v);
      }
    if (od[ti]) {
      #pragma unroll
      for (int ni = 0; ni < 4; ++ni) {
        float v = colsum[ni];
        v += __shfl_xor(v, 16, 64);
        v += __shfl_xor(v, 32, 64);
        if (l4 == 0)
          atomicAdd(&denom[col0 + wc * 64 + ni * 16 + l15], v);
      }
    }
    #pragma unroll
    for (int mi = 0; mi < 4; ++mi)
      #pragma unroll
      for (int ni = 0; ni < 4; ++ni) acc[mi][ni] = vzero;
  };

  // ---- main loop: T4 counted-vmcnt schedule (loads stay in flight across barriers) ----
  STAGE(0, 0, 0);
  #pragma unroll
  for (int s = 0; s < TOT; ++s) {
    const int buf = s & 1;
    __builtin_amdgcn_s_barrier();               // (a) all waves done reading buf[(s-1)&1]
    if (s + 1 < TOT) {
      STAGE(buf ^ 1, (s + 1) >> 2, (s + 1) & 3);
      asm volatile("s_waitcnt vmcnt(8)" ::: "memory");   // STAGE(s) landed; STAGE(s+1) in flight
    } else {
      asm volatile("s_waitcnt vmcnt(0)" ::: "memory");
    }
    __builtin_amdgcn_s_barrier();               // (b) everyone's STAGE(s) landed
    __builtin_amdgcn_sched_barrier(0);

    bf16x8 af[2][4], bfr[2][4];
    #pragma unroll
    for (int h = 0; h < 2; ++h) {
      #pragma unroll
      for (int mi = 0; mi < 4; ++mi) {
        int rl  = wr * 64 + mi * 16 + l15;
        int gsa = (h * 4 + l4) ^ (rl & 7);
        af[h][mi] = *(const bf16x8*)(&sA[buf][rl * 64 + gsa * 8]);
        int cl  = wc * 64 + mi * 16 + l15;
        int gsb = (h * 4 + l4) ^ (cl & 7);
        bfr[h][mi] = *(const bf16x8*)(&sB[buf][cl * 64 + gsb * 8]);
      }
    }
    #pragma unroll
    for (int h = 0; h < 2; ++h)
      #pragma unroll
      for (int mi = 0; mi < 4; ++mi)
        #pragma unroll
        for (int ni = 0; ni < 4; ++ni)
          acc[mi][ni] = __builtin_amdgcn_mfma_f32_16x16x32_bf16(
              af[h][mi], bfr[h][ni], acc[mi][ni], 0, 0, 0);

    if ((s & 3) == 3) EPI(s >> 2);              // tile done; overlaps in-flight staging
  }

  // ---- completion: last block computes the final loss ----
  __syncthreads();                               // drains each wave's atomics (vmcnt 0)
  if (tid == 0) {
    int done = __hip_atomic_fetch_add(cnt, 1, __ATOMIC_ACQ_REL, __HIP_MEMORY_SCOPE_AGENT);
    s_last = (done == NBLK - 1) ? 1 : 0;
  }
  __syncthreads();
  if (s_last) {
    float c = 0.f;
    #pragma unroll
    for (int i = 0; i < 32; ++i) {
      float d = __hip_atomic_load(&denom[i * 256 + tid], __ATOMIC_RELAXED,
                                  __HIP_MEMORY_SCOPE_AGENT);
      c += __logf(d + 0.1f);
    }
    #pragma unroll
    for (int i = 0; i < 16; ++i) c -= 4.0f * pair[i * 256 + tid];
    #pragma unroll
    for (int m = 32; m; m >>= 1) c += __shfl_xor(c, m, 64);
    if (lane == 0) s_red[w] = c;
    __syncthreads();
    if (tid == 0)
      out[0] = (s_red[0] + s_red[1] + s_red[2] + s_red[3]) * (1.0f / (float)TWOB);
  }
}

extern "C" void kernel_launch(void* const* d_in, const int* in_sizes, int n_in,
                              void* d_out, int out_size, void* d_ws, size_t ws_size,
                              hipStream_t stream) {
  const float* emb_i = (const float*)d_in[0];
  const float* emb_j = (const float*)d_in[1];
  const int*   tags  = (const int*)d_in[2];
  // d_in[3] = num_classes (unused)
  const int*   docs  = (const int*)d_in[4];

  char* ws = (char*)d_ws;
  bf16_t* Z     = (bf16_t*)(ws + WS_Z);
  int*    keys  = (int*)(ws + WS_KEYS);
  float*  denom = (float*)(ws + WS_DEN);
  float*  pair  = (float*)(ws + WS_PAIR);
  int*    cnt   = (int*)(ws + WS_CNT);
  float*  out   = (float*)d_out;

  prep_kernel<<<B_ROWS / 2, 256, 0, stream>>>(emb_i, emb_j, tags, docs, Z, keys, denom, pair, cnt);
  fused_kernel<<<NBLK, 256, 0, stream>>>(Z, keys, denom, pair, cnt, out);
}

// Round 10
// 132.477 us; speedup vs baseline: 1.0873x; 1.0873x over previous
//
#include <hip/hip_runtime.h>
#include <hip/hip_bf16.h>
#include <cstdint>
#include <cstddef>

#define B_ROWS 4096
#define D_DIM  256
#define TWOB   8192
static constexpr float kScale = 2.8853900817779268f; // log2(e)/TEMPERATURE, T=0.5

typedef __bf16 bf16_t;
typedef __bf16 bf16x4 __attribute__((ext_vector_type(4)));
typedef __bf16 bf16x8 __attribute__((ext_vector_type(8)));
typedef float  f32x4  __attribute__((ext_vector_type(4)));

// ---- workspace layout ----
#define WS_Z    0ull                                  // bf16 [8192][256], group-swizzled per row
#define WS_KEYS ((size_t)TWOB * D_DIM * 2)            // i32 [8192]
#define WS_DEN  (WS_KEYS + (size_t)TWOB * 4)          // f32 [8192]
#define WS_PAIR (WS_DEN + (size_t)TWOB * 4)           // f32 [4096]
#define WS_CNT  (WS_PAIR + (size_t)B_ROWS * 4)        // i32 [1]

// Swizzle: within each 64-elem K-chunk (128 B), the 8 16B-groups are permuted
// by XOR with (row&7), baked into the GLOBAL layout so linear global_load_lds
// staging lands pre-swizzled in LDS (m173) and ds_read_b128 fragment reads are
// bank-conflict-free (verified: SQ_LDS_BANK_CONFLICT == 0 in R3/R5/R7).

// ---------------- kernel 1: normalize + bf16 swizzled store + keys + zeroing + pair dots ----------------
__global__ __launch_bounds__(256) void prep_kernel(
    const float* __restrict__ emb_i, const float* __restrict__ emb_j,
    const int* __restrict__ tags, const int* __restrict__ docs,
    bf16_t* __restrict__ Z, int* __restrict__ keys,
    float* __restrict__ denom, float* __restrict__ pair, int* __restrict__ cnt)
{
  __shared__ float4 zbuf[4][64];
  const int t = threadIdx.x;
  const int lane = t & 63, w = t >> 6;
  const int b = blockIdx.x;                     // 2048 blocks
  const int rlocal = 2 * b + (w & 1);
  const int row = rlocal + (w >> 1) * B_ROWS;
  const float* src = (w >> 1) ? (emb_j + (size_t)rlocal * D_DIM)
                              : (emb_i + (size_t)rlocal * D_DIM);
  float4 v = *(const float4*)(src + lane * 4);
  float ss = v.x * v.x + v.y * v.y + v.z * v.z + v.w * v.w;
  #pragma unroll
  for (int m = 32; m; m >>= 1) ss += __shfl_xor(ss, m, 64);
  float inv = 1.0f / sqrtf(ss);
  float4 z = {v.x * inv, v.y * inv, v.z * inv, v.w * inv};
  zbuf[w][lane] = z;

  bf16x4 q;
  q[0] = (bf16_t)z.x; q[1] = (bf16_t)z.y; q[2] = (bf16_t)z.z; q[3] = (bf16_t)z.w;
  int chunk = lane >> 4;
  int g     = (lane >> 1) & 7;
  int gs    = g ^ (row & 7);
  int half  = lane & 1;
  *(bf16x4*)(Z + (size_t)row * D_DIM + chunk * 64 + gs * 8 + half * 4) = q;

  if (lane == 0) {
    keys[row] = (tags[rlocal] << 16) | docs[rlocal];  // tag<100 (7b) | doc<512 (9b)
    denom[row] = 0.f;
  }
  if (b == 0 && t == 0) cnt[0] = 0;
  __syncthreads();
  if (w < 2) {  // pair dot from fp32 z (pre-rounding)
    float4 a = zbuf[w][lane], c = zbuf[w + 2][lane];
    float d = a.x * c.x + a.y * c.y + a.z * c.z + a.w * c.w;
    #pragma unroll
    for (int m = 32; m; m >>= 1) d += __shfl_xor(d, m, 64);
    if (lane == 0) pair[2 * b + w] = d;
  }
}

// ---------------- kernel 2: 256x256-tile triangular fused sim-GEMM, 8 waves, 1-barrier dbuf ----------------
#define BM   256
#define BK   64
#define NRT  (TWOB / BM)            // 32 row tiles
#define NTIL (NRT * (NRT + 1) / 2)  // 528 triangle tiles
#define NBLK 256                    // exactly 1 block/CU (LDS 128KB); tiles split 2-3 per block

__global__ __launch_bounds__(512, 2) void fused_kernel(
    const bf16_t* __restrict__ Z, const int* __restrict__ keys,
    float* __restrict__ denom, const float* __restrict__ pair,
    int* __restrict__ cnt, float* __restrict__ out)
{
  __shared__ bf16_t sA[2][BM * BK];   // 2 x 32 KB
  __shared__ bf16_t sB[2][BM * BK];   // 2 x 32 KB
  __shared__ int s_last;
  __shared__ float s_red[8];
  const int tid  = threadIdx.x;
  const int lane = tid & 63;
  const int w    = tid >> 6;          // 8 waves
  const int wr = w >> 2, wc = w & 3;  // 2x4 wave grid; per-wave output 128x64
  const int l15 = lane & 15, l4 = lane >> 4;

  // XCD-aware swizzle (256 = 8 * 32)
  const int bid = (blockIdx.x & 7) * (NBLK / 8) + (blockIdx.x >> 3);

  auto decode = [](int t, int& rt, int& ct) {
    int r = (int)((sqrtf(8.0f * (float)t + 1.0f) - 1.0f) * 0.5f);
    while ((r + 1) * (r + 2) / 2 <= t) ++r;
    while (r * (r + 1) / 2 > t) --r;
    rt = r; ct = t - r * (r + 1) / 2;
  };
  // tiles: bid, bid+256, (bid<16: bid+512)
  const bool has3 = (bid < NTIL - 2 * NBLK);
  int rt, ct;
  decode(bid, rt, ct);
  const int r0a = rt * BM, c0a = ct * BM; const bool oda = (rt != ct);
  decode(bid + NBLK, rt, ct);
  const int r0b = rt * BM, c0b = ct * BM; const bool odb = (rt != ct);
  int r0c = 0, c0c = 0; bool odc = false;
  if (has3) { decode(bid + 2 * NBLK, rt, ct); r0c = rt * BM; c0c = ct * BM; odc = (rt != ct); }

  f32x4 acc[8][4];
  const f32x4 vzero = {0.f, 0.f, 0.f, 0.f};
  #pragma unroll
  for (int mi = 0; mi < 8; ++mi)
    #pragma unroll
    for (int ni = 0; ni < 4; ++ni) acc[mi][ni] = vzero;

  // stage both 256x64 panels of (row0/col0, K-step kt) into buf: 8x16B per thread
  auto STAGE = [&](int buf, int row0, int col0, int kt) {
    #pragma unroll
    for (int i = 0; i < 4; ++i) {
      int o  = i * 8192 + tid * 16;            // byte offset within 32KB panel
      int rl = o >> 7, ob = o & 127;
      const bf16_t* ga = Z + (size_t)(row0 + rl) * D_DIM + kt * 64 + (ob >> 1);
      __builtin_amdgcn_global_load_lds(
          (const __attribute__((address_space(1))) void*)ga,
          (__attribute__((address_space(3))) void*)((char*)&sA[buf][0] + o), 16, 0, 0);
      const bf16_t* gb = Z + (size_t)(col0 + rl) * D_DIM + kt * 64 + (ob >> 1);
      __builtin_amdgcn_global_load_lds(
          (const __attribute__((address_space(1))) void*)gb,
          (__attribute__((address_space(3))) void*)((char*)&sB[buf][0] + o), 16, 0, 0);
    }
  };

  auto COMPUTE = [&](int buf) {
    #pragma unroll
    for (int h = 0; h < 2; ++h) {
      bf16x8 bfr[4];
      #pragma unroll
      for (int ni = 0; ni < 4; ++ni) {
        int cl  = wc * 64 + ni * 16 + l15;
        int gsb = (h * 4 + l4) ^ (cl & 7);
        bfr[ni] = *(const bf16x8*)(&sB[buf][cl * 64 + gsb * 8]);
      }
      #pragma unroll
      for (int mi = 0; mi < 8; ++mi) {
        int rl  = wr * 128 + mi * 16 + l15;
        int gsa = (h * 4 + l4) ^ (rl & 7);
        bf16x8 af = *(const bf16x8*)(&sA[buf][rl * 64 + gsa * 8]);
        #pragma unroll
        for (int ni = 0; ni < 4; ++ni)
          acc[mi][ni] = __builtin_amdgcn_mfma_f32_16x16x32_bf16(
              af, bfr[ni], acc[mi][ni], 0, 0, 0);
      }
    }
  };

  auto EPI = [&](int row0, int col0, bool od) {
    int keyc[4];
    #pragma unroll
    for (int ni = 0; ni < 4; ++ni)
      keyc[ni] = keys[col0 + wc * 64 + ni * 16 + l15];
    float colsum[4] = {0.f, 0.f, 0.f, 0.f};
    #pragma unroll
    for (int mi = 0; mi < 8; ++mi) {
      int keyr[4];
      #pragma unroll
      for (int j = 0; j < 4; ++j)
        keyr[j] = keys[row0 + wr * 128 + mi * 16 + l4 * 4 + j];
      float rowsum[4] = {0.f, 0.f, 0.f, 0.f};
      #pragma unroll
      for (int ni = 0; ni < 4; ++ni) {
        #pragma unroll
        for (int j = 0; j < 4; ++j) {
          int x = keyr[j] ^ keyc[ni];
          bool m = ((x >> 16) != 0) & ((x & 0xFFFF) != 0);
          float e = m ? __builtin_amdgcn_exp2f(acc[mi][ni][j] * kScale) : 0.f;
          rowsum[j] += e;
          colsum[ni] += e;
        }
        acc[mi][ni] = vzero;                   // reset for next tile
      }
      #pragma unroll
      for (int j = 0; j < 4; ++j) {
        float v = rowsum[j];
        v += __shfl_xor(v, 1, 64);
        v += __shfl_xor(v, 2, 64);
        v += __shfl_xor(v, 4, 64);
        v += __shfl_xor(v, 8, 64);
        if (l15 == 0)
          atomicAdd(&denom[row0 + wr * 128 + mi * 16 + l4 * 4 + j], v);
      }
    }
    if (od) {
      #pragma unroll
      for (int ni = 0; ni < 4; ++ni) {
        float v = colsum[ni];
        v += __shfl_xor(v, 16, 64);
        v += __shfl_xor(v, 32, 64);
        if (l4 == 0)
          atomicAdd(&denom[col0 + wc * 64 + ni * 16 + l15], v);
      }
    }
  };

  // One barrier per K-step: syncthreads drains this wave's STAGE(s) (implicit
  // vmcnt) and retires all waves' reads of the buffer STAGE(s+1) overwrites.
  auto TILE = [&](int row0, int col0, bool od, bool don, int nr, int nc) {
    #pragma unroll
    for (int kt = 0; kt < 4; ++kt) {
      const int buf = kt & 1;
      __syncthreads();                         // buf staged & safe; buf^1 free
      if (kt < 3)      STAGE(buf ^ 1, row0, col0, kt + 1);
      else if (don)    STAGE(buf ^ 1, nr, nc, 0);
      COMPUTE(buf);
      if (kt == 3) EPI(row0, col0, od);
    }
  };

  STAGE(0, r0a, c0a, 0);
  TILE(r0a, c0a, oda, true, r0b, c0b);
  TILE(r0b, c0b, odb, has3, r0c, c0c);
  if (has3) TILE(r0c, c0c, odc, false, 0, 0);

  // ---- completion: last block computes the final loss ----
  __syncthreads();                             // drains this block's atomics
  if (tid == 0) {
    int done = __hip_atomic_fetch_add(cnt, 1, __ATOMIC_ACQ_REL, __HIP_MEMORY_SCOPE_AGENT);
    s_last = (done == NBLK - 1) ? 1 : 0;
  }
  __syncthreads();
  if (s_last) {
    float c = 0.f;
    #pragma unroll
    for (int i = 0; i < 16; ++i) {
      float d = __hip_atomic_load(&denom[i * 512 + tid], __ATOMIC_RELAXED,
                                  __HIP_MEMORY_SCOPE_AGENT);
      c += __logf(d + 0.1f);
    }
    #pragma unroll
    for (int i = 0; i < 8; ++i) c -= 4.0f * pair[i * 512 + tid];
    #pragma unroll
    for (int m = 32; m; m >>= 1) c += __shfl_xor(c, m, 64);
    if (lane == 0) s_red[w] = c;
    __syncthreads();
    if (tid == 0) {
      float s = 0.f;
      #pragma unroll
      for (int i = 0; i < 8; ++i) s += s_red[i];
      out[0] = s * (1.0f / (float)TWOB);
    }
  }
}

extern "C" void kernel_launch(void* const* d_in, const int* in_sizes, int n_in,
                              void* d_out, int out_size, void* d_ws, size_t ws_size,
                              hipStream_t stream) {
  const float* emb_i = (const float*)d_in[0];
  const float* emb_j = (const float*)d_in[1];
  const int*   tags  = (const int*)d_in[2];
  // d_in[3] = num_classes (unused)
  const int*   docs  = (const int*)d_in[4];

  char* ws = (char*)d_ws;
  bf16_t* Z     = (bf16_t*)(ws + WS_Z);
  int*    keys  = (int*)(ws + WS_KEYS);
  float*  denom = (float*)(ws + WS_DEN);
  float*  pair  = (float*)(ws + WS_PAIR);
  int*    cnt   = (int*)(ws + WS_CNT);
  float*  out   = (float*)d_out;

  prep_kernel<<<B_ROWS / 2, 256, 0, stream>>>(emb_i, emb_j, tags, docs, Z, keys, denom, pair, cnt);
  fused_kernel<<<NBLK, 512, 0, stream>>>(Z, keys, denom, pair, cnt, out);
}